// Round 2
// baseline (23387.831 us; speedup 1.0000x reference)
//
#include <hip/hip_runtime.h>
#include <hip/hip_bf16.h>

#define BB 64
#define VV 2048
#define ENCD 128
#define TT 100
#define EMBD 256
#define DECD 512
#define ATTD 256
#define NVOCAB 29
#define NBLK 256

typedef unsigned int u32;
typedef unsigned short u16;
typedef __attribute__((ext_vector_type(2))) float f2;

__device__ __forceinline__ float sigf(float x) { return 1.0f / (1.0f + __expf(-x)); }
__device__ __forceinline__ u16 to_bf16(float f) {
    u32 u = __float_as_uint(f);
    u += 0x7fffu + ((u >> 16) & 1u);       // round-to-nearest-even
    return (u16)(u >> 16);
}

#if __has_builtin(__builtin_amdgcn_cvt_pk_fp8_f32) && __has_builtin(__builtin_amdgcn_cvt_pk_f32_fp8)
#define HAVE_FP8_CVT 1
#endif

// fp8 e4m3fn encode (RNE, subnormals flushed to 0)
__device__ __forceinline__ u32 fp8_enc(float f) {
#ifdef HAVE_FP8_CVT
    return (u32)__builtin_amdgcn_cvt_pk_fp8_f32(f, f, 0, false) & 0xffu;
#else
    u32 u = __float_as_uint(f);
    u32 s = (u >> 24) & 0x80u;
    u32 a = u & 0x7fffffffu;
    u32 r = a + 0x7FFFFu + ((a >> 20) & 1u);
    int v = (int)(r >> 20) - (120 << 3);
    if (v < 8) v = 0;
    if (v > 0x7E) v = 0x7E;
    return s | (u32)v;
#endif
}
__device__ __forceinline__ void fp8x4_dec(u32 u, float* o) {
#ifdef HAVE_FP8_CVT
    f2 lo = __builtin_amdgcn_cvt_pk_f32_fp8((int)u, false);
    f2 hi = __builtin_amdgcn_cvt_pk_f32_fp8((int)u, true);
    o[0] = lo[0]; o[1] = lo[1]; o[2] = hi[0]; o[3] = hi[1];
#else
    #pragma unroll
    for (int i = 0; i < 4; i++) {
        u32 byte = (u >> (8 * i)) & 0xffu;
        u32 s = (byte & 0x80u) << 24;
        u32 m = byte & 0x7fu;
        o[i] = m ? __uint_as_float(s | ((m + (120u << 3)) << 20)) : __uint_as_float(s);
    }
#endif
}

// device-wide barrier: monotonic counter, agent-scope release-add; the acquire
// spin-load that observes the target count synchronizes-with every block's
// release-add (cross-XCD visibility without a standalone fence builtin).
__device__ __forceinline__ void gbar(u32* cnt, u32 idx) {
    __syncthreads();
    if (threadIdx.x == 0) {
        __hip_atomic_fetch_add(cnt, 1u, __ATOMIC_RELEASE, __HIP_MEMORY_SCOPE_AGENT);
        u32 tgt = idx * NBLK;
        while (__hip_atomic_load(cnt, __ATOMIC_ACQUIRE, __HIP_MEMORY_SCOPE_AGENT) < tgt)
            __builtin_amdgcn_s_sleep(2);
    }
    __syncthreads();
}

// ---------------- one-time init kernels ----------------

__global__ __launch_bounds__(256) void k_transpose(const float* __restrict__ W_dec,
                                                   const float* __restrict__ W_beta,
                                                   const float* __restrict__ W_ih,
                                                   float* __restrict__ W_decT,
                                                   float* __restrict__ W_betaT,
                                                   float* __restrict__ W2T) {
    int i = blockIdx.x * 256 + threadIdx.x;
    if (i < DECD * ATTD) {
        int l = i / ATTD, a = i % ATTD;
        W_decT[i] = W_dec[a * DECD + l];
    } else if (i < DECD * ATTD + DECD * ENCD) {
        int j = i - DECD * ATTD;
        int l = j / ENCD, e = j % ENCD;
        W_betaT[j] = W_beta[e * DECD + l];
    } else if (i < DECD * ATTD + DECD * ENCD + ENCD * 2048) {
        int j = i - (DECD * ATTD + DECD * ENCD);
        int e = j >> 11, g = j & 2047;
        W2T[j] = W_ih[g * 384 + 256 + e];
    }
}

__global__ __launch_bounds__(256) void k_enc_att(const float* __restrict__ enc,
                                                 const float* __restrict__ W_enc,
                                                 const float* __restrict__ b_enc,
                                                 unsigned char* __restrict__ enc_att8,
                                                 u16* __restrict__ enc_bf) {
    __shared__ float tile[64][ENCD + 1];
    int b = blockIdx.y, v0 = blockIdx.x * 64;
    int t = threadIdx.x;
    const float* src = enc + ((size_t)b * VV + v0) * ENCD;
    u16* dstb = enc_bf + ((size_t)b * VV + v0) * ENCD;
    for (int i = t; i < 64 * ENCD; i += 256) {
        float x = src[i];
        tile[i >> 7][i & 127] = x;
        dstb[i] = to_bf16(x);
    }
    __syncthreads();
    int vl = t & 63;
    int ag = __builtin_amdgcn_readfirstlane(t >> 6);
    int q = v0 >> 10, vin = (v0 & 1023) + vl;
    unsigned char* dst8 = enc_att8 + (((size_t)(b * 2 + q) * 256) << 10) + vin;
    for (int ao = 0; ao < 8; ao++) {
        int a0 = ag * 64 + ao * 8;
        float acc[8];
        #pragma unroll
        for (int j = 0; j < 8; j++) acc[j] = b_enc[a0 + j];
        const float* w = W_enc + (size_t)a0 * ENCD;
        for (int k = 0; k < ENCD; k++) {
            float x = tile[vl][k];
            #pragma unroll
            for (int j = 0; j < 8; j++) acc[j] = fmaf(x, w[j * ENCD + k], acc[j]);
        }
        #pragma unroll
        for (int j = 0; j < 8; j++)
            dst8[(size_t)(a0 + j) << 10] = (unsigned char)fp8_enc(acc[j]);
    }
}

__global__ __launch_bounds__(512) void k_init(const float* __restrict__ enc,
                                              const int* __restrict__ lens,
                                              const int* __restrict__ captions,
                                              const float* __restrict__ emb_W,
                                              const float* __restrict__ W_init_h,
                                              const float* __restrict__ b_init_h,
                                              const float* __restrict__ W_init_c,
                                              const float* __restrict__ b_init_c,
                                              const float* __restrict__ W_decT,
                                              const float* __restrict__ b_dec,
                                              const float* __restrict__ W_betaT,
                                              const float* __restrict__ b_beta,
                                              float* __restrict__ c0,
                                              float* __restrict__ xT,
                                              float* __restrict__ dec_att,
                                              float* __restrict__ gate0,
                                              float* __restrict__ out_len) {
    __shared__ float part[512];
    __shared__ float mean[ENCD];
    __shared__ float h_s[DECD];
    int b = blockIdx.x, t = threadIdx.x;
    int e = t & 127, ch = t >> 7;
    float s = 0.f;
    const float* rowb = enc + (size_t)b * VV * ENCD;
    for (int v = ch * 512; v < ch * 512 + 512; v++) s += rowb[(size_t)v * ENCD + e];
    part[t] = s;
    __syncthreads();
    if (ch == 0) mean[e] = (part[e] + part[128 + e] + part[256 + e] + part[384 + e]) * (1.0f / VV);
    __syncthreads();
    {
        int d = t;
        float hh = b_init_h[d], cc = b_init_c[d];
        for (int k = 0; k < ENCD; k++) {
            hh = fmaf(mean[k], W_init_h[d * ENCD + k], hh);
            cc = fmaf(mean[k], W_init_c[d * ENCD + k], cc);
        }
        c0[b * DECD + d] = cc;
        h_s[d] = hh;
        xT[(384 + d) * BB + b] = hh;
    }
    __syncthreads();
    if (t < ATTD) {
        float s2 = b_dec[t];
        for (int l = 0; l < DECD; l++) s2 = fmaf(h_s[l], W_decT[l * ATTD + t], s2);
        dec_att[b * ATTD + t] = s2;
    } else if (t < ATTD + ENCD) {
        int ee = t - ATTD;
        float s2 = b_beta[ee];
        for (int l = 0; l < DECD; l++) s2 = fmaf(h_s[l], W_betaT[l * ENCD + ee], s2);
        gate0[b * ENCD + ee] = sigf(s2);
    } else {
        int k = t - 384;
        int cap = captions[b * TT + 0];
        xT[k * BB + b] = emb_W[cap * EMBD + k];
        xT[(k + 128) * BB + b] = emb_W[cap * EMBD + k + 128];
    }
    if (t == 0) out_len[b] = (float)lens[b];
}

// ---------------- fused persistent loop kernel ----------------
// 256 blocks x 512 threads, cooperative launch (all co-resident, 1 block/CU).
// Per step: phase A = scores/awe (blocks 0..63, one b per block) + LSTM partial
// GEMM (blocks 64..255); gbar; phase B = cell (blocks 0..127, (b,part)); gbar.
// Math is identical to the previous k_att/k_cell pair — only the launch overhead
// of 200 dependent dispatches is replaced by in-kernel device barriers.

struct LoopArgs {
    const unsigned char* enc_att8;
    const u16* enc_bf;
    const float* w_full;
    const int* lens;
    const int* captions;
    const float* emb_W;
    const float* W_ih;
    const float* W_hh;
    const float* b_ih;
    const float* b_hh;
    const float* W2T;
    const float* W_final;
    const float* b_final;
    const float* W_decT;
    const float* b_dec;
    const float* W_betaT;
    const float* b_beta;
    u16* escoreT;
    float* dpartT;
    float* pawe;
    float* gates_part;
    float* dec_att;
    float* gate0;
    float* gate1;
    float* c0;
    float* c1;
    float* xT;
    float* preds;
    u32* bar;
};

__global__ __launch_bounds__(512) void k_loop(LoopArgs A) {
    // phase A score: esh[2][1024] @0, redw[2][4][128] @2048, dred[2][4] @3072
    // phase B cell : gawe[128] @0, h_s[512] @128, red[512] @640
    __shared__ float smem[3080];
    const int blk = blockIdx.x;
    const int t = threadIdx.x;
    const int lane = t & 63;
    const int wv8 = t >> 6;

    const int len_score = (blk < 64) ? A.lens[blk] : 0;
    const int len_cell  = (blk < 128) ? A.lens[blk >> 1] : 0;

    u32 baridx = 0;

    for (int ts = 0; ts < TT; ++ts) {
        // ------------- phase A -------------
        if (blk < 64) {
            if (ts < len_score) {
                const int b = blk;
                const int q = t >> 8, tq = t & 255, wv = wv8 & 3;
                const u32* sp = (const u32*)A.enc_att8 + (((size_t)(b * 2 + q)) << 16) + tq;
                const float* db = A.dec_att + b * ATTD;   // uniform addr -> s_load
                float s0 = 0.f, s1 = 0.f, s2 = 0.f, s3 = 0.f;
                #pragma unroll 8
                for (int a = 0; a < ATTD; a++) {
                    u32 u = sp[(size_t)a * 256];          // contiguous 1KB-stride stream
                    float x[4];
                    fp8x4_dec(u, x);
                    float da = db[a], wf = A.w_full[a];   // b_full dropped (softmax shift-inv)
                    s0 = fmaf(fmaxf(x[0] + da, 0.f), wf, s0);
                    s1 = fmaf(fmaxf(x[1] + da, 0.f), wf, s1);
                    s2 = fmaf(fmaxf(x[2] + da, 0.f), wf, s2);
                    s3 = fmaf(fmaxf(x[3] + da, 0.f), wf, s3);
                }
                float e0 = __expf(s0), e1 = __expf(s1), e2 = __expf(s2), e3 = __expf(s3);
                uint2 pk;
                pk.x = (u32)to_bf16(e0) | ((u32)to_bf16(e1) << 16);
                pk.y = (u32)to_bf16(e2) | ((u32)to_bf16(e3) << 16);
                ((uint2*)A.escoreT)[(((size_t)ts * BB + b) * VV + (q << 10)) / 4 + tq] = pk;
                smem[q * 1024 + 4 * tq]     = e0;
                smem[q * 1024 + 4 * tq + 1] = e1;
                smem[q * 1024 + 4 * tq + 2] = e2;
                smem[q * 1024 + 4 * tq + 3] = e3;
                float ss = e0 + e1 + e2 + e3;
                for (int o = 32; o > 0; o >>= 1) ss += __shfl_down(ss, o);
                if (lane == 0) smem[3072 + q * 4 + wv] = ss;
                __syncthreads();
                if (tq == 0)
                    A.dpartT[((size_t)ts * BB + b) * 2 + q] =
                        smem[3072 + q * 4] + smem[3072 + q * 4 + 1] +
                        smem[3072 + q * 4 + 2] + smem[3072 + q * 4 + 3];
                // awe partial from bf16 encoder, e-pairs packed in u32
                const u32* eb = (const u32*)A.enc_bf +
                                ((size_t)b * VV + (q << 10)) * (ENCD / 2) + lane;
                float a0 = 0.f, a1 = 0.f;
                #pragma unroll 8
                for (int vv = wv; vv < 1024; vv += 4) {
                    u32 u = eb[(size_t)vv * 64];
                    float sc = smem[q * 1024 + vv];       // wave-uniform -> broadcast
                    a0 = fmaf(__uint_as_float(u << 16), sc, a0);
                    a1 = fmaf(__uint_as_float(u & 0xffff0000u), sc, a1);
                }
                smem[2048 + (q * 4 + wv) * 128 + 2 * lane]     = a0;
                smem[2048 + (q * 4 + wv) * 128 + 2 * lane + 1] = a1;
                __syncthreads();
                if (tq < ENCD)
                    A.pawe[((size_t)b * 2 + q) * ENCD + tq] =
                        smem[2048 + (q * 4) * 128 + tq] + smem[2048 + (q * 4 + 1) * 128 + tq] +
                        smem[2048 + (q * 4 + 2) * 128 + tq] + smem[2048 + (q * 4 + 3) * 128 + tq];
            }
        } else {
            // LSTM gate partial GEMM: 192 blocks = 6 K-slots x 32 gate-groups
            int idx = blk - 64;
            int kcp = idx >> 5;                 // slot 0..5
            int kc = kcp < 2 ? kcp : kcp + 1;   // K chunk {0,1,3,4,5,6}
            int gt = idx & 31;
            int gbase = gt * 64 + wv8 * 8;
            int gb = __builtin_amdgcn_readfirstlane(gbase);  // scalar weight addressing
            int k0 = kc * 128;
            float acc[8];
            #pragma unroll
            for (int j = 0; j < 8; j++)
                acc[j] = (kc == 0) ? (A.b_ih[gb + j] + A.b_hh[gb + j]) : 0.f;
            if (kc < 2) {                        // emb columns 0..255
                for (int kk = 0; kk < 128; kk++) {
                    float xv = A.xT[(k0 + kk) * BB + lane];
                    #pragma unroll
                    for (int j = 0; j < 8; j++)
                        acc[j] = fmaf(xv, A.W_ih[(gb + j) * 384 + k0 + kk], acc[j]);
                }
            } else {                             // h columns (W_hh cols 0..511)
                const float* Wh = A.W_hh + (k0 - 384);
                for (int kk = 0; kk < 128; kk++) {
                    float xv = A.xT[(k0 + kk) * BB + lane];
                    #pragma unroll
                    for (int j = 0; j < 8; j++)
                        acc[j] = fmaf(xv, Wh[(gb + j) * DECD + kk], acc[j]);
                }
            }
            float4* o4 = (float4*)(A.gates_part + ((size_t)kcp * BB + lane) * 2048 + gbase);
            o4[0] = make_float4(acc[0], acc[1], acc[2], acc[3]);
            o4[1] = make_float4(acc[4], acc[5], acc[6], acc[7]);
        }
        gbar(A.bar, ++baridx);

        // ------------- phase B -------------
        if (blk < 128 && ts < len_cell) {
            const int b = blk >> 1, part = blk & 1;
            float* gawe_s = smem;
            float* h_s    = smem + 128;
            float* red    = smem + 640;
            const float* dp = A.dpartT + ((size_t)ts * BB + b) * 2;
            float inv = 1.0f / (dp[0] + dp[1]);
            const float* gprev = (ts & 1) ? A.gate1 : A.gate0;
            float*       gnext = (ts & 1) ? A.gate0 : A.gate1;
            if (t < ENCD) {
                const float* pw = A.pawe + (size_t)b * 2 * ENCD + t;
                float aw = (pw[0] + pw[ENCD]) * inv;
                gawe_s[t] = gprev[b * ENCD + t] * aw;
            }
            __syncthreads();
            const float* cin  = (ts & 1) ? A.c1 : A.c0;
            float*       cout = (ts & 1) ? A.c0 : A.c1;
            {
                float gi = 0.f, gf = 0.f, gg = 0.f, go = 0.f;
                #pragma unroll
                for (int sc = 0; sc < 6; sc++) {
                    const float* gp = A.gates_part + ((size_t)sc * BB + b) * 2048;
                    gi += gp[t]; gf += gp[512 + t]; gg += gp[1024 + t]; go += gp[1536 + t];
                }
                #pragma unroll 4
                for (int e = 0; e < ENCD; e++) {   // kc2: coalesced W2T rows, gawe broadcast
                    const float* w = A.W2T + (size_t)e * 2048;
                    float ge = gawe_s[e];
                    gi = fmaf(w[t], ge, gi);
                    gf = fmaf(w[512 + t], ge, gf);
                    gg = fmaf(w[1024 + t], ge, gg);
                    go = fmaf(w[1536 + t], ge, go);
                }
                gi = sigf(gi); gf = sigf(gf); go = sigf(go); gg = tanhf(gg);
                float cn = fmaf(gf, cin[b * DECD + t], gi * gg);
                float hn = go * tanhf(cn);
                h_s[t] = hn;
                if (part == 0) {
                    cout[b * DECD + t] = cn;
                    A.xT[(384 + t) * BB + b] = hn;
                }
            }
            __syncthreads();
            if (part == 0) {
                int a = t & 255, half = t >> 8;
                float s = 0.f;
                const float* wd = A.W_decT + (size_t)half * 256 * ATTD + a;
                #pragma unroll 4
                for (int l = 0; l < 256; l++)
                    s = fmaf(h_s[half * 256 + l], wd[(size_t)l * ATTD], s);
                red[t] = s;
                __syncthreads();
                if (t < 256) {
                    A.dec_att[b * ATTD + t] = red[t] + red[t + 256] + A.b_dec[t];
                } else if (ts + 1 < TT) {          // emb staging for ts+1
                    int k = t - 256;
                    int cap = A.captions[b * TT + ts + 1];
                    A.xT[k * BB + b] = A.emb_W[cap * EMBD + k];
                }
            } else {
                int e = t & 127, qq = t >> 7;
                float s = 0.f;
                const float* wb = A.W_betaT + (size_t)qq * 128 * ENCD + e;
                #pragma unroll 4
                for (int l = 0; l < 128; l++)
                    s = fmaf(h_s[qq * 128 + l], wb[(size_t)l * ENCD], s);
                red[t] = s;
                __syncthreads();
                if (t < 128)
                    gnext[b * ENCD + t] = sigf(red[t] + red[t + 128] + red[t + 256] +
                                               red[t + 384] + A.b_beta[t]);
                for (int j = wv8; j < NVOCAB; j += 8) {
                    float s2 = 0.f;
                    #pragma unroll
                    for (int i = 0; i < 8; i++)
                        s2 = fmaf(h_s[lane + 64 * i], A.W_final[j * DECD + lane + 64 * i], s2);
                    for (int o = 32; o > 0; o >>= 1) s2 += __shfl_down(s2, o);
                    if (lane == 0) A.preds[((size_t)b * TT + ts) * NVOCAB + j] = s2 + A.b_final[j];
                }
            }
        }
        gbar(A.bar, ++baridx);
    }
}

// bulk alphas: alphas[b][ts][v] = bf16(escoreT[ts][b][v]) / denom[ts][b]
__global__ __launch_bounds__(256) void k_alphas(const u16* __restrict__ escoreT,
                                                const float* __restrict__ dpartT,
                                                const int* __restrict__ lens,
                                                float* __restrict__ alphas) {
    int ts = blockIdx.x, b = blockIdx.y, t = threadIdx.x;
    if (ts >= lens[b]) return;             // output pre-zeroed
    const float* dp = dpartT + ((size_t)ts * BB + b) * 2;
    float inv = 1.0f / (dp[0] + dp[1]);
    const u32* es = (const u32*)escoreT + ((size_t)ts * BB + b) * VV / 2;
    float2* al = (float2*)(alphas + ((size_t)b * TT + ts) * VV);
    #pragma unroll
    for (int i = t; i < VV / 2; i += 256) {
        u32 u = es[i];
        al[i] = make_float2(__uint_as_float(u << 16) * inv,
                            __uint_as_float(u & 0xffff0000u) * inv);
    }
}

extern "C" void kernel_launch(void* const* d_in, const int* in_sizes, int n_in,
                              void* d_out, int out_size, void* d_ws, size_t ws_size,
                              hipStream_t stream) {
    const float* enc      = (const float*)d_in[0];
    const int*   captions = (const int*)d_in[1];
    const int*   lens     = (const int*)d_in[2];
    const float* emb_W    = (const float*)d_in[3];
    const float* W_enc    = (const float*)d_in[4];
    const float* b_enc    = (const float*)d_in[5];
    const float* W_dec    = (const float*)d_in[6];
    const float* b_dec    = (const float*)d_in[7];
    const float* w_full   = (const float*)d_in[8];
    // d_in[9] b_full: unused — softmax is shift-invariant
    const float* W_ih     = (const float*)d_in[10];
    const float* b_ih     = (const float*)d_in[11];
    const float* W_hh     = (const float*)d_in[12];
    const float* b_hh     = (const float*)d_in[13];
    const float* W_init_h = (const float*)d_in[14];
    const float* b_init_h = (const float*)d_in[15];
    const float* W_init_c = (const float*)d_in[16];
    const float* b_init_c = (const float*)d_in[17];
    const float* W_beta   = (const float*)d_in[18];
    const float* b_beta   = (const float*)d_in[19];
    const float* W_final  = (const float*)d_in[20];
    const float* b_final  = (const float*)d_in[21];

    float* preds   = (float*)d_out;                      // [B][T][VOCAB]
    float* alphas  = preds + (size_t)BB * TT * NVOCAB;   // [B][T][V]
    float* out_len = alphas + (size_t)BB * TT * VV;      // [B] (as float)

    char* ws = (char*)d_ws;
    size_t off = 0;
    auto alloc = [&](size_t bytes) {
        char* p = ws + off;
        off += (bytes + 255) & ~(size_t)255;
        return p;
    };
    unsigned char* enc_att8 = (unsigned char*)alloc((size_t)BB * ATTD * VV);   // 33.5 MB fp8
    u16*   enc_bf     = (u16*)  alloc((size_t)BB * VV * ENCD * sizeof(u16));   // 33.5 MB
    u16*   escoreT    = (u16*)  alloc((size_t)TT * BB * VV * sizeof(u16));     // 26.2 MB
    float* dpartT     = (float*)alloc((size_t)TT * BB * 2 * sizeof(float));
    float* pawe       = (float*)alloc((size_t)BB * 2 * ENCD * sizeof(float));
    float* dec_att    = (float*)alloc((size_t)BB * ATTD * sizeof(float));
    float* gate0      = (float*)alloc((size_t)BB * ENCD * sizeof(float));
    float* gate1      = (float*)alloc((size_t)BB * ENCD * sizeof(float));
    float* xT         = (float*)alloc((size_t)896 * BB * sizeof(float));
    float* gates_part = (float*)alloc((size_t)6 * BB * 2048 * sizeof(float));
    float* c0         = (float*)alloc((size_t)BB * DECD * sizeof(float));
    float* c1         = (float*)alloc((size_t)BB * DECD * sizeof(float));
    float* W_decT     = (float*)alloc((size_t)DECD * ATTD * sizeof(float));
    float* W_betaT    = (float*)alloc((size_t)DECD * ENCD * sizeof(float));
    float* W2T        = (float*)alloc((size_t)ENCD * 2048 * sizeof(float));
    u32*   bar        = (u32*)  alloc(256);              // barrier counter

    hipMemsetAsync(d_out, 0, (size_t)out_size * sizeof(float), stream);
    hipMemsetAsync(bar, 0, sizeof(u32), stream);         // reset per launch (graph replay)

    k_transpose<<<1792, 256, 0, stream>>>(W_dec, W_beta, W_ih, W_decT, W_betaT, W2T);
    k_enc_att<<<dim3(VV / 64, BB), 256, 0, stream>>>(enc, W_enc, b_enc, enc_att8, enc_bf);
    k_init<<<BB, 512, 0, stream>>>(enc, lens, captions, emb_W, W_init_h, b_init_h,
                                   W_init_c, b_init_c, W_decT, b_dec, W_betaT, b_beta,
                                   c0, xT, dec_att, gate0, out_len);

    LoopArgs la;
    la.enc_att8 = enc_att8; la.enc_bf = enc_bf; la.w_full = w_full; la.lens = lens;
    la.captions = captions; la.emb_W = emb_W;
    la.W_ih = W_ih; la.W_hh = W_hh; la.b_ih = b_ih; la.b_hh = b_hh;
    la.W2T = W2T; la.W_final = W_final; la.b_final = b_final;
    la.W_decT = W_decT; la.b_dec = b_dec; la.W_betaT = W_betaT; la.b_beta = b_beta;
    la.escoreT = escoreT; la.dpartT = dpartT; la.pawe = pawe; la.gates_part = gates_part;
    la.dec_att = dec_att; la.gate0 = gate0; la.gate1 = gate1; la.c0 = c0; la.c1 = c1;
    la.xT = xT; la.preds = preds; la.bar = bar;
    void* kp[] = { &la };
    hipLaunchCooperativeKernel((const void*)k_loop, dim3(NBLK), dim3(512), kp, 0, stream);

    k_alphas<<<dim3(TT, BB), 256, 0, stream>>>(escoreT, dpartT, lens, alphas);
}

// Round 4
// 16992.584 us; speedup vs baseline: 1.3764x; 1.3764x over previous
//
#include <hip/hip_runtime.h>
#include <hip/hip_bf16.h>

#define BB 64
#define VV 2048
#define ENCD 128
#define TT 100
#define EMBD 256
#define DECD 512
#define ATTD 256
#define NVOCAB 29
#define NBLK 256

typedef unsigned int u32;
typedef unsigned short u16;
typedef __attribute__((ext_vector_type(2))) float f2;

__device__ __forceinline__ float sigf(float x) { return 1.0f / (1.0f + __expf(-x)); }
__device__ __forceinline__ u16 to_bf16(float f) {
    u32 u = __float_as_uint(f);
    u += 0x7fffu + ((u >> 16) & 1u);       // round-to-nearest-even
    return (u16)(u >> 16);
}

#if __has_builtin(__builtin_amdgcn_cvt_pk_fp8_f32) && __has_builtin(__builtin_amdgcn_cvt_pk_f32_fp8)
#define HAVE_FP8_CVT 1
#endif

// fp8 e4m3fn encode (RNE, subnormals flushed to 0)
__device__ __forceinline__ u32 fp8_enc(float f) {
#ifdef HAVE_FP8_CVT
    return (u32)__builtin_amdgcn_cvt_pk_fp8_f32(f, f, 0, false) & 0xffu;
#else
    u32 u = __float_as_uint(f);
    u32 s = (u >> 24) & 0x80u;
    u32 a = u & 0x7fffffffu;
    u32 r = a + 0x7FFFFu + ((a >> 20) & 1u);
    int v = (int)(r >> 20) - (120 << 3);
    if (v < 8) v = 0;
    if (v > 0x7E) v = 0x7E;
    return s | (u32)v;
#endif
}
__device__ __forceinline__ void fp8x4_dec(u32 u, float* o) {
#ifdef HAVE_FP8_CVT
    f2 lo = __builtin_amdgcn_cvt_pk_f32_fp8((int)u, false);
    f2 hi = __builtin_amdgcn_cvt_pk_f32_fp8((int)u, true);
    o[0] = lo[0]; o[1] = lo[1]; o[2] = hi[0]; o[3] = hi[1];
#else
    #pragma unroll
    for (int i = 0; i < 4; i++) {
        u32 byte = (u >> (8 * i)) & 0xffu;
        u32 s = (byte & 0x80u) << 24;
        u32 m = byte & 0x7fu;
        o[i] = m ? __uint_as_float(s | ((m + (120u << 3)) << 20)) : __uint_as_float(s);
    }
#endif
}

// Coherence protocol — relaxed agent-scope atomics only (no release/acquire,
// so no buffer_inv/wbl2 cache-maintenance storms):
//  stc: relaxed agent atomic store  -> write-through to LLC (scope flag
//       bypasses the non-coherent per-XCD L2)
//  ldc: relaxed agent atomic load   -> reads from LLC (scope flag bypass)
// Every buffer REWRITTEN by k_loop is accessed exclusively via stc/ldc.
// Read-only data (inputs, pre-loop workspace) uses normal cached loads.
// __syncthreads() drains vmcnt(0) per wave before s_barrier, so all of a
// block's stc stores are LLC-visible before its barrier arrival RMW.
__device__ __forceinline__ void stc(float* p, float v) {
    __hip_atomic_store(p, v, __ATOMIC_RELAXED, __HIP_MEMORY_SCOPE_AGENT);
}
__device__ __forceinline__ float ldc(const float* p) {
    return __hip_atomic_load((float*)p, __ATOMIC_RELAXED, __HIP_MEMORY_SCOPE_AGENT);
}
__device__ __forceinline__ u32 ldcu(const u32* p) {
    return __hip_atomic_load((u32*)p, __ATOMIC_RELAXED, __HIP_MEMORY_SCOPE_AGENT);
}

// device-wide barrier: 8 spaced arrival counters (RMWs execute at the
// coherence point -> progress-safe), block 0 detects completion and
// broadcasts a monotonic go-epoch; others spin on the epoch with relaxed
// scope loads + s_sleep.
__device__ __forceinline__ void gbar(u32* bar, int blk, u32 idx) {
    __syncthreads();
    asm volatile("" ::: "memory");
    if (threadIdx.x == 0) {
        __hip_atomic_fetch_add(&bar[(blk & 7) * 32], 1u, __ATOMIC_RELAXED,
                               __HIP_MEMORY_SCOPE_AGENT);
        if (blk == 0) {
            u32 s;
            do {
                s = 0;
                #pragma unroll
                for (int i = 0; i < 8; i++) s += ldcu(&bar[i * 32]);
                if (s < idx * NBLK) __builtin_amdgcn_s_sleep(1);
            } while (s < idx * NBLK);
            __hip_atomic_store(&bar[512], idx, __ATOMIC_RELAXED,
                               __HIP_MEMORY_SCOPE_AGENT);
        } else {
            while (ldcu(&bar[512]) < idx) __builtin_amdgcn_s_sleep(2);
        }
    }
    asm volatile("" ::: "memory");
    __syncthreads();
}

// ---------------- one-time init kernels ----------------

__global__ __launch_bounds__(256) void k_transpose(const float* __restrict__ W_dec,
                                                   const float* __restrict__ W_beta,
                                                   const float* __restrict__ W_ih,
                                                   float* __restrict__ W_decT,
                                                   float* __restrict__ W_betaT,
                                                   float* __restrict__ W2T) {
    int i = blockIdx.x * 256 + threadIdx.x;
    if (i < DECD * ATTD) {
        int l = i / ATTD, a = i % ATTD;
        W_decT[i] = W_dec[a * DECD + l];
    } else if (i < DECD * ATTD + DECD * ENCD) {
        int j = i - DECD * ATTD;
        int l = j / ENCD, e = j % ENCD;
        W_betaT[j] = W_beta[e * DECD + l];
    } else if (i < DECD * ATTD + DECD * ENCD + ENCD * 2048) {
        int j = i - (DECD * ATTD + DECD * ENCD);
        int e = j >> 11, g = j & 2047;
        W2T[j] = W_ih[g * 384 + 256 + e];
    }
}

__global__ __launch_bounds__(256) void k_enc_att(const float* __restrict__ enc,
                                                 const float* __restrict__ W_enc,
                                                 const float* __restrict__ b_enc,
                                                 unsigned char* __restrict__ enc_att8,
                                                 u16* __restrict__ enc_bf) {
    __shared__ float tile[64][ENCD + 1];
    int b = blockIdx.y, v0 = blockIdx.x * 64;
    int t = threadIdx.x;
    const float* src = enc + ((size_t)b * VV + v0) * ENCD;
    u16* dstb = enc_bf + ((size_t)b * VV + v0) * ENCD;
    for (int i = t; i < 64 * ENCD; i += 256) {
        float x = src[i];
        tile[i >> 7][i & 127] = x;
        dstb[i] = to_bf16(x);
    }
    __syncthreads();
    int vl = t & 63;
    int ag = __builtin_amdgcn_readfirstlane(t >> 6);
    int q = v0 >> 10, vin = (v0 & 1023) + vl;
    unsigned char* dst8 = enc_att8 + (((size_t)(b * 2 + q) * 256) << 10) + vin;
    for (int ao = 0; ao < 8; ao++) {
        int a0 = ag * 64 + ao * 8;
        float acc[8];
        #pragma unroll
        for (int j = 0; j < 8; j++) acc[j] = b_enc[a0 + j];
        const float* w = W_enc + (size_t)a0 * ENCD;
        for (int k = 0; k < ENCD; k++) {
            float x = tile[vl][k];
            #pragma unroll
            for (int j = 0; j < 8; j++) acc[j] = fmaf(x, w[j * ENCD + k], acc[j]);
        }
        #pragma unroll
        for (int j = 0; j < 8; j++)
            dst8[(size_t)(a0 + j) << 10] = (unsigned char)fp8_enc(acc[j]);
    }
}

__global__ __launch_bounds__(512) void k_init(const float* __restrict__ enc,
                                              const int* __restrict__ lens,
                                              const int* __restrict__ captions,
                                              const float* __restrict__ emb_W,
                                              const float* __restrict__ W_init_h,
                                              const float* __restrict__ b_init_h,
                                              const float* __restrict__ W_init_c,
                                              const float* __restrict__ b_init_c,
                                              const float* __restrict__ W_decT,
                                              const float* __restrict__ b_dec,
                                              const float* __restrict__ W_betaT,
                                              const float* __restrict__ b_beta,
                                              float* __restrict__ c0,
                                              float* __restrict__ xT,
                                              float* __restrict__ dec_att,
                                              float* __restrict__ gate0,
                                              float* __restrict__ out_len) {
    __shared__ float part[512];
    __shared__ float mean[ENCD];
    __shared__ float h_s[DECD];
    int b = blockIdx.x, t = threadIdx.x;
    int e = t & 127, ch = t >> 7;
    float s = 0.f;
    const float* rowb = enc + (size_t)b * VV * ENCD;
    for (int v = ch * 512; v < ch * 512 + 512; v++) s += rowb[(size_t)v * ENCD + e];
    part[t] = s;
    __syncthreads();
    if (ch == 0) mean[e] = (part[e] + part[128 + e] + part[256 + e] + part[384 + e]) * (1.0f / VV);
    __syncthreads();
    {
        int d = t;
        float hh = b_init_h[d], cc = b_init_c[d];
        for (int k = 0; k < ENCD; k++) {
            hh = fmaf(mean[k], W_init_h[d * ENCD + k], hh);
            cc = fmaf(mean[k], W_init_c[d * ENCD + k], cc);
        }
        c0[b * DECD + d] = cc;
        h_s[d] = hh;
        xT[(384 + d) * BB + b] = hh;
    }
    __syncthreads();
    if (t < ATTD) {
        float s2 = b_dec[t];
        for (int l = 0; l < DECD; l++) s2 = fmaf(h_s[l], W_decT[l * ATTD + t], s2);
        dec_att[b * ATTD + t] = s2;
    } else if (t < ATTD + ENCD) {
        int ee = t - ATTD;
        float s2 = b_beta[ee];
        for (int l = 0; l < DECD; l++) s2 = fmaf(h_s[l], W_betaT[l * ENCD + ee], s2);
        gate0[b * ENCD + ee] = sigf(s2);
    } else {
        int k = t - 384;
        int cap = captions[b * TT + 0];
        xT[k * BB + b] = emb_W[cap * EMBD + k];
        xT[(k + 128) * BB + b] = emb_W[cap * EMBD + k + 128];
    }
    if (t == 0) out_len[b] = (float)lens[b];
}

// ---------------- fused persistent loop kernel ----------------
// 256 blocks x 512 threads, cooperative launch (1 block/CU, persistent).
// Per step: phase A = scores/awe (blocks 0..63) + LSTM partial GEMM (64..255);
// gbar; phase B = cell (blocks 0..127); gbar. Single buffers (round-2 memory
// footprint); all k_loop-rewritten buffers accessed via stc/ldc only.

struct LoopArgs {
    const unsigned char* enc_att8;
    const u16* enc_bf;
    const float* w_full;
    const int* lens;
    const int* captions;
    const float* emb_W;
    const float* W_ih;
    const float* W_hh;
    const float* b_ih;
    const float* b_hh;
    const float* W2T;
    const float* W_final;
    const float* b_final;
    const float* W_decT;
    const float* b_dec;
    const float* W_betaT;
    const float* b_beta;
    u16* escoreT;       // [TT][BB][VV] bf16 (read post-loop only)
    float* dpartT;      // [TT][BB][2]
    float* pawe;        // [BB][2][ENCD]
    float* gates_part;  // [6][BB][2048]
    float* dec_att;     // [BB][ATTD]
    float* gate0;       // [BB][ENCD]
    float* gate1;
    float* c0;          // [BB][DECD]
    float* c1;
    float* xT;          // [896][BB]
    float* preds;
    u32* bar;
};

__global__ __launch_bounds__(512) void k_loop(LoopArgs A) {
    // smem layout:
    //  score: esh[2048] @0, redw[1024] @2048, dred[8] @3072, da_s[256] @3104
    //  gemm : xs[8192] @0
    //  cell : gawe[128] @0, h_s[512] @128, red[512] @640
    __shared__ float smem[8192];
    const int blk = blockIdx.x;
    const int t = threadIdx.x;
    const int lane = t & 63;
    const int wv8 = t >> 6;

    const int len_score = (blk < 64) ? A.lens[blk] : 0;
    const int len_cell  = (blk < 128) ? A.lens[blk >> 1] : 0;

    u32 baridx = 0;

    for (int ts = 0; ts < TT; ++ts) {
        // ------------- phase A -------------
        if (blk < 64) {
            if (ts < len_score) {
                const int b = blk;
                const int q = t >> 8, tq = t & 255, wv = wv8 & 3;
                float* esh  = smem;
                float* redw = smem + 2048;
                float* dred = smem + 3072;
                float* da_s = smem + 3104;
                if (t < ATTD) da_s[t] = ldc(A.dec_att + b * ATTD + t);
                __syncthreads();
                const u32* sp = (const u32*)A.enc_att8 + (((size_t)(b * 2 + q)) << 16) + tq;
                float s0 = 0.f, s1 = 0.f, s2 = 0.f, s3 = 0.f;
                #pragma unroll 8
                for (int a = 0; a < ATTD; a++) {
                    u32 u = sp[(size_t)a * 256];          // contiguous 1KB-stride stream
                    float x[4];
                    fp8x4_dec(u, x);
                    float da = da_s[a], wf = A.w_full[a]; // b_full dropped (softmax shift-inv)
                    s0 = fmaf(fmaxf(x[0] + da, 0.f), wf, s0);
                    s1 = fmaf(fmaxf(x[1] + da, 0.f), wf, s1);
                    s2 = fmaf(fmaxf(x[2] + da, 0.f), wf, s2);
                    s3 = fmaf(fmaxf(x[3] + da, 0.f), wf, s3);
                }
                float e0 = __expf(s0), e1 = __expf(s1), e2 = __expf(s2), e3 = __expf(s3);
                uint2 pk;
                pk.x = (u32)to_bf16(e0) | ((u32)to_bf16(e1) << 16);
                pk.y = (u32)to_bf16(e2) | ((u32)to_bf16(e3) << 16);
                ((uint2*)A.escoreT)[(((size_t)ts * BB + b) * VV + (q << 10)) / 4 + tq] = pk;
                esh[q * 1024 + 4 * tq]     = e0;
                esh[q * 1024 + 4 * tq + 1] = e1;
                esh[q * 1024 + 4 * tq + 2] = e2;
                esh[q * 1024 + 4 * tq + 3] = e3;
                float ss = e0 + e1 + e2 + e3;
                for (int o = 32; o > 0; o >>= 1) ss += __shfl_down(ss, o);
                if (lane == 0) dred[q * 4 + wv] = ss;
                __syncthreads();
                if (tq == 0)
                    stc(&A.dpartT[((size_t)ts * BB + b) * 2 + q],
                        dred[q * 4] + dred[q * 4 + 1] + dred[q * 4 + 2] + dred[q * 4 + 3]);
                // awe partial from bf16 encoder, e-pairs packed in u32
                const u32* eb = (const u32*)A.enc_bf +
                                ((size_t)b * VV + (q << 10)) * (ENCD / 2) + lane;
                float a0 = 0.f, a1 = 0.f;
                #pragma unroll 8
                for (int vv = wv; vv < 1024; vv += 4) {
                    u32 u = eb[(size_t)vv * 64];
                    float sc = esh[q * 1024 + vv];        // wave-uniform -> broadcast
                    a0 = fmaf(__uint_as_float(u << 16), sc, a0);
                    a1 = fmaf(__uint_as_float(u & 0xffff0000u), sc, a1);
                }
                redw[(q * 4 + wv) * 128 + 2 * lane]     = a0;
                redw[(q * 4 + wv) * 128 + 2 * lane + 1] = a1;
                __syncthreads();
                if (tq < ENCD)
                    stc(&A.pawe[((size_t)b * 2 + q) * ENCD + tq],
                        redw[(q * 4) * 128 + tq] + redw[(q * 4 + 1) * 128 + tq] +
                        redw[(q * 4 + 2) * 128 + tq] + redw[(q * 4 + 3) * 128 + tq]);
            }
        } else {
            // LSTM gate partial GEMM: 192 blocks = 6 K-slots x 32 gate-groups
            int idx = blk - 64;
            int kcp = idx >> 5;                 // slot 0..5
            int kc = kcp < 2 ? kcp : kcp + 1;   // K chunk {0,1,3,4,5,6}
            int gt = idx & 31;
            int gbase = gt * 64 + wv8 * 8;
            int gb = __builtin_amdgcn_readfirstlane(gbase);  // scalar weight addressing
            int k0 = kc * 128;
            // stage this block's 128x64 x-chunk into LDS via coherent loads
            float* xs = smem;
            const float* xsrc = A.xT + (size_t)k0 * BB;
            #pragma unroll
            for (int i = 0; i < 16; i++) xs[t + i * 512] = ldc(xsrc + t + i * 512);
            __syncthreads();
            float acc[8];
            #pragma unroll
            for (int j = 0; j < 8; j++)
                acc[j] = (kc == 0) ? (A.b_ih[gb + j] + A.b_hh[gb + j]) : 0.f;
            if (kc < 2) {                        // emb columns 0..255
                for (int kk = 0; kk < 128; kk++) {
                    float xv = xs[kk * BB + lane];
                    #pragma unroll
                    for (int j = 0; j < 8; j++)
                        acc[j] = fmaf(xv, A.W_ih[(gb + j) * 384 + k0 + kk], acc[j]);
                }
            } else {                             // h columns (W_hh cols 0..511)
                const float* Wh = A.W_hh + (k0 - 384);
                for (int kk = 0; kk < 128; kk++) {
                    float xv = xs[kk * BB + lane];
                    #pragma unroll
                    for (int j = 0; j < 8; j++)
                        acc[j] = fmaf(xv, Wh[(gb + j) * DECD + kk], acc[j]);
                }
            }
            float* o = A.gates_part + ((size_t)kcp * BB + lane) * 2048 + gbase;
            #pragma unroll
            for (int j = 0; j < 8; j++) stc(o + j, acc[j]);
        }
        gbar(A.bar, blk, ++baridx);

        // ------------- phase B -------------
        if (blk < 128 && ts < len_cell) {
            const int b = blk >> 1, part = blk & 1;
            float* gawe_s = smem;
            float* h_s    = smem + 128;
            float* red    = smem + 640;
            const float* dp = A.dpartT + ((size_t)ts * BB + b) * 2;
            float inv = 1.0f / (ldc(dp) + ldc(dp + 1));
            const float* gprev = (ts & 1) ? A.gate1 : A.gate0;   // ping-pong
            float*       gnext = (ts & 1) ? A.gate0 : A.gate1;
            if (t < ENCD) {
                const float* pw = A.pawe + (size_t)b * 2 * ENCD + t;
                float aw = (ldc(pw) + ldc(pw + ENCD)) * inv;
                gawe_s[t] = ldc(gprev + b * ENCD + t) * aw;
            }
            __syncthreads();
            const float* cin  = (ts & 1) ? A.c1 : A.c0;
            float*       cout = (ts & 1) ? A.c0 : A.c1;
            {
                float gv[24];
                #pragma unroll
                for (int sc = 0; sc < 6; sc++) {
                    const float* gp = A.gates_part + ((size_t)sc * BB + b) * 2048;
                    gv[sc * 4 + 0] = ldc(gp + t);
                    gv[sc * 4 + 1] = ldc(gp + 512 + t);
                    gv[sc * 4 + 2] = ldc(gp + 1024 + t);
                    gv[sc * 4 + 3] = ldc(gp + 1536 + t);
                }
                float gi = 0.f, gf = 0.f, gg = 0.f, go = 0.f;
                #pragma unroll
                for (int sc = 0; sc < 6; sc++) {   // same slot order as before
                    gi += gv[sc * 4 + 0]; gf += gv[sc * 4 + 1];
                    gg += gv[sc * 4 + 2]; go += gv[sc * 4 + 3];
                }
                #pragma unroll 4
                for (int e = 0; e < ENCD; e++) {   // kc2: coalesced W2T rows, gawe broadcast
                    const float* w = A.W2T + (size_t)e * 2048;
                    float ge = gawe_s[e];
                    gi = fmaf(w[t], ge, gi);
                    gf = fmaf(w[512 + t], ge, gf);
                    gg = fmaf(w[1024 + t], ge, gg);
                    go = fmaf(w[1536 + t], ge, go);
                }
                gi = sigf(gi); gf = sigf(gf); go = sigf(go); gg = tanhf(gg);
                float cn = fmaf(gf, ldc(cin + b * DECD + t), gi * gg);
                float hn = go * tanhf(cn);
                h_s[t] = hn;
                if (part == 0) {
                    stc(cout + b * DECD + t, cn);
                    stc(A.xT + (384 + t) * BB + b, hn);
                }
            }
            __syncthreads();
            if (part == 0) {
                int a = t & 255, half = t >> 8;    // dec_att: 256 a, K split 2 ways
                float s = 0.f;
                const float* wd = A.W_decT + (size_t)half * 256 * ATTD + a;
                #pragma unroll 4
                for (int l = 0; l < 256; l++)
                    s = fmaf(h_s[half * 256 + l], wd[(size_t)l * ATTD], s);
                red[t] = s;
                __syncthreads();
                if (t < 256) {
                    stc(A.dec_att + b * ATTD + t, red[t] + red[t + 256] + A.b_dec[t]);
                } else if (ts + 1 < TT) {          // emb staging for ts+1
                    int k = t - 256;
                    int cap = A.captions[b * TT + ts + 1];
                    stc(A.xT + k * BB + b, A.emb_W[cap * EMBD + k]);
                }
            } else {
                int e = t & 127, qq = t >> 7;      // gate: 128 e, K split 4 ways
                float s = 0.f;
                const float* wb = A.W_betaT + (size_t)qq * 128 * ENCD + e;
                #pragma unroll 4
                for (int l = 0; l < 128; l++)
                    s = fmaf(h_s[qq * 128 + l], wb[(size_t)l * ENCD], s);
                red[t] = s;
                __syncthreads();
                if (t < 128)
                    stc(gnext + b * ENCD + t,
                        sigf(red[t] + red[t + 128] + red[t + 256] + red[t + 384] + A.b_beta[t]));
                for (int j = wv8; j < NVOCAB; j += 8) {   // predictions: 8 waves, 29 vocab
                    float s2 = 0.f;
                    #pragma unroll
                    for (int i = 0; i < 8; i++)
                        s2 = fmaf(h_s[lane + 64 * i], A.W_final[j * DECD + lane + 64 * i], s2);
                    for (int o = 32; o > 0; o >>= 1) s2 += __shfl_down(s2, o);
                    if (lane == 0) A.preds[((size_t)b * TT + ts) * NVOCAB + j] = s2 + A.b_final[j];
                }
            }
        }
        gbar(A.bar, blk, ++baridx);
    }
}

// bulk alphas: alphas[b][ts][v] = bf16(escoreT[ts][b][v]) / denom[ts][b]
__global__ __launch_bounds__(256) void k_alphas(const u16* __restrict__ escoreT,
                                                const float* __restrict__ dpartT,
                                                const int* __restrict__ lens,
                                                float* __restrict__ alphas) {
    int ts = blockIdx.x, b = blockIdx.y, t = threadIdx.x;
    if (ts >= lens[b]) return;             // output pre-zeroed
    const float* dp = dpartT + ((size_t)ts * BB + b) * 2;
    float inv = 1.0f / (dp[0] + dp[1]);
    const u32* es = (const u32*)escoreT + ((size_t)ts * BB + b) * VV / 2;
    float2* al = (float2*)(alphas + ((size_t)b * TT + ts) * VV);
    #pragma unroll
    for (int i = t; i < VV / 2; i += 256) {
        u32 u = es[i];
        al[i] = make_float2(__uint_as_float(u << 16) * inv,
                            __uint_as_float(u & 0xffff0000u) * inv);
    }
}

extern "C" void kernel_launch(void* const* d_in, const int* in_sizes, int n_in,
                              void* d_out, int out_size, void* d_ws, size_t ws_size,
                              hipStream_t stream) {
    const float* enc      = (const float*)d_in[0];
    const int*   captions = (const int*)d_in[1];
    const int*   lens     = (const int*)d_in[2];
    const float* emb_W    = (const float*)d_in[3];
    const float* W_enc    = (const float*)d_in[4];
    const float* b_enc    = (const float*)d_in[5];
    const float* W_dec    = (const float*)d_in[6];
    const float* b_dec    = (const float*)d_in[7];
    const float* w_full   = (const float*)d_in[8];
    // d_in[9] b_full: unused — softmax is shift-invariant
    const float* W_ih     = (const float*)d_in[10];
    const float* b_ih     = (const float*)d_in[11];
    const float* W_hh     = (const float*)d_in[12];
    const float* b_hh     = (const float*)d_in[13];
    const float* W_init_h = (const float*)d_in[14];
    const float* b_init_h = (const float*)d_in[15];
    const float* W_init_c = (const float*)d_in[16];
    const float* b_init_c = (const float*)d_in[17];
    const float* W_beta   = (const float*)d_in[18];
    const float* b_beta   = (const float*)d_in[19];
    const float* W_final  = (const float*)d_in[20];
    const float* b_final  = (const float*)d_in[21];

    float* preds   = (float*)d_out;                      // [B][T][VOCAB]
    float* alphas  = preds + (size_t)BB * TT * NVOCAB;   // [B][T][V]
    float* out_len = alphas + (size_t)BB * TT * VV;      // [B] (as float)

    char* ws = (char*)d_ws;
    size_t off = 0;
    auto alloc = [&](size_t bytes) {
        char* p = ws + off;
        off += (bytes + 255) & ~(size_t)255;
        return p;
    };
    // total ~98.9 MB — identical footprint to the round-2 kernel that ran
    unsigned char* enc_att8 = (unsigned char*)alloc((size_t)BB * ATTD * VV);   // 33.5 MB fp8
    u16*   enc_bf     = (u16*)  alloc((size_t)BB * VV * ENCD * sizeof(u16));   // 33.5 MB
    u16*   escoreT    = (u16*)  alloc((size_t)TT * BB * VV * sizeof(u16));     // 26.2 MB
    float* dpartT     = (float*)alloc((size_t)TT * BB * 2 * sizeof(float));
    float* pawe       = (float*)alloc((size_t)BB * 2 * ENCD * sizeof(float));
    float* dec_att    = (float*)alloc((size_t)BB * ATTD * sizeof(float));
    float* gate0      = (float*)alloc((size_t)BB * ENCD * sizeof(float));
    float* gate1      = (float*)alloc((size_t)BB * ENCD * sizeof(float));
    float* xT         = (float*)alloc((size_t)896 * BB * sizeof(float));
    float* gates_part = (float*)alloc((size_t)6 * BB * 2048 * sizeof(float));  // 3.1 MB
    float* c0         = (float*)alloc((size_t)BB * DECD * sizeof(float));
    float* c1         = (float*)alloc((size_t)BB * DECD * sizeof(float));
    float* W_decT     = (float*)alloc((size_t)DECD * ATTD * sizeof(float));
    float* W_betaT    = (float*)alloc((size_t)DECD * ENCD * sizeof(float));
    float* W2T        = (float*)alloc((size_t)ENCD * 2048 * sizeof(float));
    u32*   bar        = (u32*)  alloc(4096);             // barrier counters + go

    hipMemsetAsync(d_out, 0, (size_t)out_size * sizeof(float), stream);
    hipMemsetAsync(bar, 0, 4096, stream);                // reset per launch (graph replay)

    k_transpose<<<1792, 256, 0, stream>>>(W_dec, W_beta, W_ih, W_decT, W_betaT, W2T);
    k_enc_att<<<dim3(VV / 64, BB), 256, 0, stream>>>(enc, W_enc, b_enc, enc_att8, enc_bf);
    k_init<<<BB, 512, 0, stream>>>(enc, lens, captions, emb_W, W_init_h, b_init_h,
                                   W_init_c, b_init_c, W_decT, b_dec, W_betaT, b_beta,
                                   c0, xT, dec_att, gate0, out_len);

    LoopArgs la;
    la.enc_att8 = enc_att8; la.enc_bf = enc_bf; la.w_full = w_full; la.lens = lens;
    la.captions = captions; la.emb_W = emb_W;
    la.W_ih = W_ih; la.W_hh = W_hh; la.b_ih = b_ih; la.b_hh = b_hh;
    la.W2T = W2T; la.W_final = W_final; la.b_final = b_final;
    la.W_decT = W_decT; la.b_dec = b_dec; la.W_betaT = W_betaT; la.b_beta = b_beta;
    la.escoreT = escoreT; la.dpartT = dpartT; la.pawe = pawe; la.gates_part = gates_part;
    la.dec_att = dec_att; la.gate0 = gate0; la.gate1 = gate1; la.c0 = c0; la.c1 = c1;
    la.xT = xT; la.preds = preds; la.bar = bar;
    void* kp[] = { &la };
    hipLaunchCooperativeKernel((const void*)k_loop, dim3(NBLK), dim3(512), kp, 0, stream);

    k_alphas<<<dim3(TT, BB), 256, 0, stream>>>(escoreT, dpartT, lens, alphas);
}

// Round 5
// 11835.013 us; speedup vs baseline: 1.9762x; 1.4358x over previous
//
#include <hip/hip_runtime.h>
#include <hip/hip_bf16.h>

#define BB 64
#define VV 2048
#define ENCD 128
#define TT 100
#define EMBD 256
#define DECD 512
#define ATTD 256
#define NVOCAB 29
#define NBLK 256

typedef unsigned int u32;
typedef unsigned short u16;
typedef __attribute__((ext_vector_type(2))) float f2;
typedef __attribute__((ext_vector_type(4))) float f4;

__device__ __forceinline__ float sigf(float x) { return 1.0f / (1.0f + __expf(-x)); }
__device__ __forceinline__ u16 to_bf16(float f) {
    u32 u = __float_as_uint(f);
    u += 0x7fffu + ((u >> 16) & 1u);       // round-to-nearest-even
    return (u16)(u >> 16);
}

#if __has_builtin(__builtin_amdgcn_cvt_pk_fp8_f32) && __has_builtin(__builtin_amdgcn_cvt_pk_f32_fp8)
#define HAVE_FP8_CVT 1
#endif

// fp8 e4m3fn encode (RNE, subnormals flushed to 0)
__device__ __forceinline__ u32 fp8_enc(float f) {
#ifdef HAVE_FP8_CVT
    return (u32)__builtin_amdgcn_cvt_pk_fp8_f32(f, f, 0, false) & 0xffu;
#else
    u32 u = __float_as_uint(f);
    u32 s = (u >> 24) & 0x80u;
    u32 a = u & 0x7fffffffu;
    u32 r = a + 0x7FFFFu + ((a >> 20) & 1u);
    int v = (int)(r >> 20) - (120 << 3);
    if (v < 8) v = 0;
    if (v > 0x7E) v = 0x7E;
    return s | (u32)v;
#endif
}
__device__ __forceinline__ void fp8x4_dec(u32 u, float* o) {
#ifdef HAVE_FP8_CVT
    f2 lo = __builtin_amdgcn_cvt_pk_f32_fp8((int)u, false);
    f2 hi = __builtin_amdgcn_cvt_pk_f32_fp8((int)u, true);
    o[0] = lo[0]; o[1] = lo[1]; o[2] = hi[0]; o[3] = hi[1];
#else
    #pragma unroll
    for (int i = 0; i < 4; i++) {
        u32 byte = (u >> (8 * i)) & 0xffu;
        u32 s = (byte & 0x80u) << 24;
        u32 m = byte & 0x7fu;
        o[i] = m ? __uint_as_float(s | ((m + (120u << 3)) << 20)) : __uint_as_float(s);
    }
#endif
}

// Coherence protocol — relaxed agent-scope operations only (no release/acquire,
// so no cache-maintenance storms):
//  stc / ldc : relaxed agent atomic dword  (write-through LLC / LLC-read).
//              Measured r4: atomic LOADS coalesce across lanes; atomic STORES
//              do NOT (each dword -> own >=32B fabric write).
//  stg4_sc1  : non-atomic global_store_dwordx4 with sc1 (agent write-through,
//              16B per lane, lane-coalescing) — for bulk cross-block stores.
// __syncthreads() drains vmcnt(0) per wave before s_barrier, so all of a
// block's stores (incl. asm sc1 stores) are LLC-visible before its arrival RMW.
__device__ __forceinline__ void stc(float* p, float v) {
    __hip_atomic_store(p, v, __ATOMIC_RELAXED, __HIP_MEMORY_SCOPE_AGENT);
}
__device__ __forceinline__ float ldc(const float* p) {
    return __hip_atomic_load((float*)p, __ATOMIC_RELAXED, __HIP_MEMORY_SCOPE_AGENT);
}
__device__ __forceinline__ u32 ldcu(const u32* p) {
    return __hip_atomic_load((u32*)p, __ATOMIC_RELAXED, __HIP_MEMORY_SCOPE_AGENT);
}
__device__ __forceinline__ void stg4_sc1(float* p, f4 v) {
    asm volatile("global_store_dwordx4 %0, %1, off sc1" :: "v"(p), "v"(v) : "memory");
}

// device-wide barrier: 8 spaced arrival counters (RMWs execute at the
// coherence point -> progress-safe); block 0 detects completion and stores 8
// per-group go-flags (spreads spin contention 8x); blocks spin on their own
// group's flag with relaxed scope loads + s_sleep.
__device__ __forceinline__ void gbar(u32* bar, int blk, u32 idx) {
    __syncthreads();
    asm volatile("" ::: "memory");
    if (threadIdx.x == 0) {
        __hip_atomic_fetch_add(&bar[(blk & 7) * 32], 1u, __ATOMIC_RELAXED,
                               __HIP_MEMORY_SCOPE_AGENT);
        if (blk == 0) {
            u32 s;
            do {
                s = 0;
                #pragma unroll
                for (int i = 0; i < 8; i++) s += ldcu(&bar[i * 32]);
                if (s < idx * NBLK) __builtin_amdgcn_s_sleep(1);
            } while (s < idx * NBLK);
            #pragma unroll
            for (int i = 0; i < 8; i++)
                __hip_atomic_store(&bar[256 + i * 32], idx, __ATOMIC_RELAXED,
                                   __HIP_MEMORY_SCOPE_AGENT);
        } else {
            while (ldcu(&bar[256 + (blk & 7) * 32]) < idx) __builtin_amdgcn_s_sleep(2);
        }
    }
    asm volatile("" ::: "memory");
    __syncthreads();
}

// ---------------- one-time init kernels ----------------

__global__ __launch_bounds__(256) void k_transpose(const float* __restrict__ W_dec,
                                                   const float* __restrict__ W_beta,
                                                   const float* __restrict__ W_ih,
                                                   float* __restrict__ W_decT,
                                                   float* __restrict__ W_betaT,
                                                   float* __restrict__ W2T) {
    int i = blockIdx.x * 256 + threadIdx.x;
    if (i < DECD * ATTD) {
        int l = i / ATTD, a = i % ATTD;
        W_decT[i] = W_dec[a * DECD + l];
    } else if (i < DECD * ATTD + DECD * ENCD) {
        int j = i - DECD * ATTD;
        int l = j / ENCD, e = j % ENCD;
        W_betaT[j] = W_beta[e * DECD + l];
    } else if (i < DECD * ATTD + DECD * ENCD + ENCD * 2048) {
        int j = i - (DECD * ATTD + DECD * ENCD);
        int e = j >> 11, g = j & 2047;
        W2T[j] = W_ih[g * 384 + 256 + e];
    }
}

__global__ __launch_bounds__(256) void k_enc_att(const float* __restrict__ enc,
                                                 const float* __restrict__ W_enc,
                                                 const float* __restrict__ b_enc,
                                                 unsigned char* __restrict__ enc_att8,
                                                 u16* __restrict__ enc_bf) {
    __shared__ float tile[64][ENCD + 1];
    int b = blockIdx.y, v0 = blockIdx.x * 64;
    int t = threadIdx.x;
    const float* src = enc + ((size_t)b * VV + v0) * ENCD;
    u16* dstb = enc_bf + ((size_t)b * VV + v0) * ENCD;
    for (int i = t; i < 64 * ENCD; i += 256) {
        float x = src[i];
        tile[i >> 7][i & 127] = x;
        dstb[i] = to_bf16(x);
    }
    __syncthreads();
    int vl = t & 63;
    int ag = __builtin_amdgcn_readfirstlane(t >> 6);
    int q = v0 >> 10, vin = (v0 & 1023) + vl;
    unsigned char* dst8 = enc_att8 + (((size_t)(b * 2 + q) * 256) << 10) + vin;
    for (int ao = 0; ao < 8; ao++) {
        int a0 = ag * 64 + ao * 8;
        float acc[8];
        #pragma unroll
        for (int j = 0; j < 8; j++) acc[j] = b_enc[a0 + j];
        const float* w = W_enc + (size_t)a0 * ENCD;
        for (int k = 0; k < ENCD; k++) {
            float x = tile[vl][k];
            #pragma unroll
            for (int j = 0; j < 8; j++) acc[j] = fmaf(x, w[j * ENCD + k], acc[j]);
        }
        #pragma unroll
        for (int j = 0; j < 8; j++)
            dst8[(size_t)(a0 + j) << 10] = (unsigned char)fp8_enc(acc[j]);
    }
}

__global__ __launch_bounds__(512) void k_init(const float* __restrict__ enc,
                                              const int* __restrict__ lens,
                                              const int* __restrict__ captions,
                                              const float* __restrict__ emb_W,
                                              const float* __restrict__ W_init_h,
                                              const float* __restrict__ b_init_h,
                                              const float* __restrict__ W_init_c,
                                              const float* __restrict__ b_init_c,
                                              const float* __restrict__ W_decT,
                                              const float* __restrict__ b_dec,
                                              const float* __restrict__ W_betaT,
                                              const float* __restrict__ b_beta,
                                              float* __restrict__ c0,
                                              float* __restrict__ xT,
                                              float* __restrict__ dec_att,
                                              float* __restrict__ gate0,
                                              float* __restrict__ out_len) {
    __shared__ float part[512];
    __shared__ float mean[ENCD];
    __shared__ float h_s[DECD];
    int b = blockIdx.x, t = threadIdx.x;
    int e = t & 127, ch = t >> 7;
    float s = 0.f;
    const float* rowb = enc + (size_t)b * VV * ENCD;
    for (int v = ch * 512; v < ch * 512 + 512; v++) s += rowb[(size_t)v * ENCD + e];
    part[t] = s;
    __syncthreads();
    if (ch == 0) mean[e] = (part[e] + part[128 + e] + part[256 + e] + part[384 + e]) * (1.0f / VV);
    __syncthreads();
    {
        int d = t;
        float hh = b_init_h[d], cc = b_init_c[d];
        for (int k = 0; k < ENCD; k++) {
            hh = fmaf(mean[k], W_init_h[d * ENCD + k], hh);
            cc = fmaf(mean[k], W_init_c[d * ENCD + k], cc);
        }
        c0[b * DECD + d] = cc;
        h_s[d] = hh;
        xT[(384 + d) * BB + b] = hh;
    }
    __syncthreads();
    if (t < ATTD) {
        float s2 = b_dec[t];
        for (int l = 0; l < DECD; l++) s2 = fmaf(h_s[l], W_decT[l * ATTD + t], s2);
        dec_att[b * ATTD + t] = s2;
    } else if (t < ATTD + ENCD) {
        int ee = t - ATTD;
        float s2 = b_beta[ee];
        for (int l = 0; l < DECD; l++) s2 = fmaf(h_s[l], W_betaT[l * ENCD + ee], s2);
        gate0[b * ENCD + ee] = sigf(s2);
    } else {
        int k = t - 384;
        int cap = captions[b * TT + 0];
        xT[k * BB + b] = emb_W[cap * EMBD + k];
        xT[(k + 128) * BB + b] = emb_W[cap * EMBD + k + 128];
    }
    if (t == 0) out_len[b] = (float)lens[b];
}

// ---------------- fused persistent loop kernel ----------------
// 256 blocks x 512 threads, cooperative launch (1 block/CU, persistent).
// Per step: phase A = scores/awe (blocks 0..63) + LSTM partial GEMM (64..255);
// gbar; phase B = cell (blocks 0..127); gbar.

struct LoopArgs {
    const unsigned char* enc_att8;
    const u16* enc_bf;
    const float* w_full;
    const int* lens;
    const int* captions;
    const float* emb_W;
    const float* W_ih;
    const float* W_hh;
    const float* b_ih;
    const float* b_hh;
    const float* W2T;
    const float* W_final;
    const float* b_final;
    const float* W_decT;
    const float* b_dec;
    const float* W_betaT;
    const float* b_beta;
    u16* escoreT;       // [TT][BB][VV] bf16 (read post-loop only)
    float* dpartT;      // [TT][BB][2]
    float* pawe;        // [BB][2][ENCD]
    float* gates_part;  // [6][BB][2048]
    float* dec_att;     // [BB][ATTD]
    float* gate0;       // [BB][ENCD]
    float* gate1;
    float* c0;          // [BB][DECD]
    float* c1;
    float* xT;          // [896][BB]
    float* preds;
    u32* bar;
};

__global__ __launch_bounds__(512) void k_loop(LoopArgs A) {
    // smem layout:
    //  score: esh[2048] @0, redw[1024] @2048, dred[8] @3072, da_s[256] @3104
    //  gemm : xs[8192] @0
    //  cell : gawe[128] @0, h_s[512] @128, red[512] @640
    __shared__ float smem[8192];
    const int blk = blockIdx.x;
    const int t = threadIdx.x;
    const int lane = t & 63;
    const int wv8 = t >> 6;

    const int len_score = (blk < 64) ? A.lens[blk] : 0;
    const int len_cell  = (blk < 128) ? A.lens[blk >> 1] : 0;

    u32 baridx = 0;

    for (int ts = 0; ts < TT; ++ts) {
        // ------------- phase A -------------
        if (blk < 64) {
            if (ts < len_score) {
                const int b = blk;
                const int q = t >> 8, tq = t & 255, wv = wv8 & 3;
                float* esh  = smem;
                float* redw = smem + 2048;
                float* dred = smem + 3072;
                float* da_s = smem + 3104;
                if (t < ATTD) da_s[t] = ldc(A.dec_att + b * ATTD + t);
                __syncthreads();
                const u32* sp = (const u32*)A.enc_att8 + (((size_t)(b * 2 + q)) << 16) + tq;
                float s0 = 0.f, s1 = 0.f, s2 = 0.f, s3 = 0.f;
                #pragma unroll 16
                for (int a = 0; a < ATTD; a++) {
                    u32 u = sp[(size_t)a * 256];          // contiguous 1KB-stride stream
                    float x[4];
                    fp8x4_dec(u, x);
                    float da = da_s[a], wf = A.w_full[a]; // b_full dropped (softmax shift-inv)
                    s0 = fmaf(fmaxf(x[0] + da, 0.f), wf, s0);
                    s1 = fmaf(fmaxf(x[1] + da, 0.f), wf, s1);
                    s2 = fmaf(fmaxf(x[2] + da, 0.f), wf, s2);
                    s3 = fmaf(fmaxf(x[3] + da, 0.f), wf, s3);
                }
                float e0 = __expf(s0), e1 = __expf(s1), e2 = __expf(s2), e3 = __expf(s3);
                uint2 pk;
                pk.x = (u32)to_bf16(e0) | ((u32)to_bf16(e1) << 16);
                pk.y = (u32)to_bf16(e2) | ((u32)to_bf16(e3) << 16);
                ((uint2*)A.escoreT)[(((size_t)ts * BB + b) * VV + (q << 10)) / 4 + tq] = pk;
                esh[q * 1024 + 4 * tq]     = e0;
                esh[q * 1024 + 4 * tq + 1] = e1;
                esh[q * 1024 + 4 * tq + 2] = e2;
                esh[q * 1024 + 4 * tq + 3] = e3;
                float ss = e0 + e1 + e2 + e3;
                for (int o = 32; o > 0; o >>= 1) ss += __shfl_down(ss, o);
                if (lane == 0) dred[q * 4 + wv] = ss;
                __syncthreads();
                if (tq == 0)
                    stc(&A.dpartT[((size_t)ts * BB + b) * 2 + q],
                        dred[q * 4] + dred[q * 4 + 1] + dred[q * 4 + 2] + dred[q * 4 + 3]);
                // awe partial from bf16 encoder, e-pairs packed in u32
                const u32* eb = (const u32*)A.enc_bf +
                                ((size_t)b * VV + (q << 10)) * (ENCD / 2) + lane;
                float a0 = 0.f, a1 = 0.f;
                #pragma unroll 16
                for (int vv = wv; vv < 1024; vv += 4) {
                    u32 u = eb[(size_t)vv * 64];
                    float sc = esh[q * 1024 + vv];        // wave-uniform -> broadcast
                    a0 = fmaf(__uint_as_float(u << 16), sc, a0);
                    a1 = fmaf(__uint_as_float(u & 0xffff0000u), sc, a1);
                }
                redw[(q * 4 + wv) * 128 + 2 * lane]     = a0;
                redw[(q * 4 + wv) * 128 + 2 * lane + 1] = a1;
                __syncthreads();
                if (tq < ENCD)
                    stc(&A.pawe[((size_t)b * 2 + q) * ENCD + tq],
                        redw[(q * 4) * 128 + tq] + redw[(q * 4 + 1) * 128 + tq] +
                        redw[(q * 4 + 2) * 128 + tq] + redw[(q * 4 + 3) * 128 + tq]);
            }
        } else {
            // LSTM gate partial GEMM: 192 blocks = 6 K-slots x 32 gate-groups
            int idx = blk - 64;
            int kcp = idx >> 5;                 // slot 0..5
            int kc = kcp < 2 ? kcp : kcp + 1;   // K chunk {0,1,3,4,5,6}
            int gt = idx & 31;
            int gbase = gt * 64 + wv8 * 8;
            int gb = __builtin_amdgcn_readfirstlane(gbase);  // scalar weight addressing
            int k0 = kc * 128;
            // stage this block's 128x64 x-chunk into LDS via coherent loads
            float* xs = smem;
            const float* xsrc = A.xT + (size_t)k0 * BB;
            #pragma unroll
            for (int i = 0; i < 16; i++) xs[t + i * 512] = ldc(xsrc + t + i * 512);
            __syncthreads();
            float acc[8];
            #pragma unroll
            for (int j = 0; j < 8; j++)
                acc[j] = (kc == 0) ? (A.b_ih[gb + j] + A.b_hh[gb + j]) : 0.f;
            if (kc < 2) {                        // emb columns 0..255
                for (int kk = 0; kk < 128; kk++) {
                    float xv = xs[kk * BB + lane];
                    #pragma unroll
                    for (int j = 0; j < 8; j++)
                        acc[j] = fmaf(xv, A.W_ih[(gb + j) * 384 + k0 + kk], acc[j]);
                }
            } else {                             // h columns (W_hh cols 0..511)
                const float* Wh = A.W_hh + (k0 - 384);
                for (int kk = 0; kk < 128; kk++) {
                    float xv = xs[kk * BB + lane];
                    #pragma unroll
                    for (int j = 0; j < 8; j++)
                        acc[j] = fmaf(xv, Wh[(gb + j) * DECD + kk], acc[j]);
                }
            }
            // bulk coherent store: 2x dwordx4 sc1 (coalescing write-through)
            float* o = A.gates_part + ((size_t)kcp * BB + lane) * 2048 + gbase;
            f4 lo, hi;
            lo.x = acc[0]; lo.y = acc[1]; lo.z = acc[2]; lo.w = acc[3];
            hi.x = acc[4]; hi.y = acc[5]; hi.z = acc[6]; hi.w = acc[7];
            stg4_sc1(o, lo);
            stg4_sc1(o + 4, hi);
        }
        gbar(A.bar, blk, ++baridx);

        // ------------- phase B -------------
        if (blk < 128 && ts < len_cell) {
            const int b = blk >> 1, part = blk & 1;
            float* gawe_s = smem;
            float* h_s    = smem + 128;
            float* red    = smem + 640;
            const float* dp = A.dpartT + ((size_t)ts * BB + b) * 2;
            float inv = 1.0f / (ldc(dp) + ldc(dp + 1));
            const float* gprev = (ts & 1) ? A.gate1 : A.gate0;   // ping-pong
            float*       gnext = (ts & 1) ? A.gate0 : A.gate1;
            if (t < ENCD) {
                const float* pw = A.pawe + (size_t)b * 2 * ENCD + t;
                float aw = (ldc(pw) + ldc(pw + ENCD)) * inv;
                gawe_s[t] = ldc(gprev + b * ENCD + t) * aw;
            }
            __syncthreads();
            const float* cin  = (ts & 1) ? A.c1 : A.c0;
            float*       cout = (ts & 1) ? A.c0 : A.c1;
            {
                float gv[24];
                #pragma unroll
                for (int sc = 0; sc < 6; sc++) {
                    const float* gp = A.gates_part + ((size_t)sc * BB + b) * 2048;
                    gv[sc * 4 + 0] = ldc(gp + t);
                    gv[sc * 4 + 1] = ldc(gp + 512 + t);
                    gv[sc * 4 + 2] = ldc(gp + 1024 + t);
                    gv[sc * 4 + 3] = ldc(gp + 1536 + t);
                }
                float gi = 0.f, gf = 0.f, gg = 0.f, go = 0.f;
                #pragma unroll
                for (int sc = 0; sc < 6; sc++) {   // same slot order as before
                    gi += gv[sc * 4 + 0]; gf += gv[sc * 4 + 1];
                    gg += gv[sc * 4 + 2]; go += gv[sc * 4 + 3];
                }
                #pragma unroll 4
                for (int e = 0; e < ENCD; e++) {   // kc2: coalesced W2T rows, gawe broadcast
                    const float* w = A.W2T + (size_t)e * 2048;
                    float ge = gawe_s[e];
                    gi = fmaf(w[t], ge, gi);
                    gf = fmaf(w[512 + t], ge, gf);
                    gg = fmaf(w[1024 + t], ge, gg);
                    go = fmaf(w[1536 + t], ge, go);
                }
                gi = sigf(gi); gf = sigf(gf); go = sigf(go); gg = tanhf(gg);
                float cn = fmaf(gf, ldc(cin + b * DECD + t), gi * gg);
                float hn = go * tanhf(cn);
                h_s[t] = hn;
                if (part == 0) {
                    stc(cout + b * DECD + t, cn);
                    stc(A.xT + (384 + t) * BB + b, hn);
                }
            }
            __syncthreads();
            if (part == 0) {
                int a = t & 255, half = t >> 8;    // dec_att: 256 a, K split 2 ways
                float s = 0.f;
                const float* wd = A.W_decT + (size_t)half * 256 * ATTD + a;
                #pragma unroll 4
                for (int l = 0; l < 256; l++)
                    s = fmaf(h_s[half * 256 + l], wd[(size_t)l * ATTD], s);
                red[t] = s;
                __syncthreads();
                if (t < 256) {
                    stc(A.dec_att + b * ATTD + t, red[t] + red[t + 256] + A.b_dec[t]);
                } else if (ts + 1 < TT) {          // emb staging for ts+1
                    int k = t - 256;
                    int cap = A.captions[b * TT + ts + 1];
                    stc(A.xT + k * BB + b, A.emb_W[cap * EMBD + k]);
                }
            } else {
                int e = t & 127, qq = t >> 7;      // gate: 128 e, K split 4 ways
                float s = 0.f;
                const float* wb = A.W_betaT + (size_t)qq * 128 * ENCD + e;
                #pragma unroll 4
                for (int l = 0; l < 128; l++)
                    s = fmaf(h_s[qq * 128 + l], wb[(size_t)l * ENCD], s);
                red[t] = s;
                __syncthreads();
                if (t < 128)
                    stc(gnext + b * ENCD + t,
                        sigf(red[t] + red[t + 128] + red[t + 256] + red[t + 384] + A.b_beta[t]));
                for (int j = wv8; j < NVOCAB; j += 8) {   // predictions: 8 waves, 29 vocab
                    float s2 = 0.f;
                    #pragma unroll
                    for (int i = 0; i < 8; i++)
                        s2 = fmaf(h_s[lane + 64 * i], A.W_final[j * DECD + lane + 64 * i], s2);
                    for (int o = 32; o > 0; o >>= 1) s2 += __shfl_down(s2, o);
                    if (lane == 0) A.preds[((size_t)b * TT + ts) * NVOCAB + j] = s2 + A.b_final[j];
                }
            }
        }
        gbar(A.bar, blk, ++baridx);
    }
}

// bulk alphas: alphas[b][ts][v] = bf16(escoreT[ts][b][v]) / denom[ts][b]
__global__ __launch_bounds__(256) void k_alphas(const u16* __restrict__ escoreT,
                                                const float* __restrict__ dpartT,
                                                const int* __restrict__ lens,
                                                float* __restrict__ alphas) {
    int ts = blockIdx.x, b = blockIdx.y, t = threadIdx.x;
    if (ts >= lens[b]) return;             // output pre-zeroed
    const float* dp = dpartT + ((size_t)ts * BB + b) * 2;
    float inv = 1.0f / (dp[0] + dp[1]);
    const u32* es = (const u32*)escoreT + ((size_t)ts * BB + b) * VV / 2;
    float2* al = (float2*)(alphas + ((size_t)b * TT + ts) * VV);
    #pragma unroll
    for (int i = t; i < VV / 2; i += 256) {
        u32 u = es[i];
        al[i] = make_float2(__uint_as_float(u << 16) * inv,
                            __uint_as_float(u & 0xffff0000u) * inv);
    }
}

extern "C" void kernel_launch(void* const* d_in, const int* in_sizes, int n_in,
                              void* d_out, int out_size, void* d_ws, size_t ws_size,
                              hipStream_t stream) {
    const float* enc      = (const float*)d_in[0];
    const int*   captions = (const int*)d_in[1];
    const int*   lens     = (const int*)d_in[2];
    const float* emb_W    = (const float*)d_in[3];
    const float* W_enc    = (const float*)d_in[4];
    const float* b_enc    = (const float*)d_in[5];
    const float* W_dec    = (const float*)d_in[6];
    const float* b_dec    = (const float*)d_in[7];
    const float* w_full   = (const float*)d_in[8];
    // d_in[9] b_full: unused — softmax is shift-invariant
    const float* W_ih     = (const float*)d_in[10];
    const float* b_ih     = (const float*)d_in[11];
    const float* W_hh     = (const float*)d_in[12];
    const float* b_hh     = (const float*)d_in[13];
    const float* W_init_h = (const float*)d_in[14];
    const float* b_init_h = (const float*)d_in[15];
    const float* W_init_c = (const float*)d_in[16];
    const float* b_init_c = (const float*)d_in[17];
    const float* W_beta   = (const float*)d_in[18];
    const float* b_beta   = (const float*)d_in[19];
    const float* W_final  = (const float*)d_in[20];
    const float* b_final  = (const float*)d_in[21];

    float* preds   = (float*)d_out;                      // [B][T][VOCAB]
    float* alphas  = preds + (size_t)BB * TT * NVOCAB;   // [B][T][V]
    float* out_len = alphas + (size_t)BB * TT * VV;      // [B] (as float)

    char* ws = (char*)d_ws;
    size_t off = 0;
    auto alloc = [&](size_t bytes) {
        char* p = ws + off;
        off += (bytes + 255) & ~(size_t)255;
        return p;
    };
    // total ~98.9 MB — identical footprint to the round-4 kernel that ran
    unsigned char* enc_att8 = (unsigned char*)alloc((size_t)BB * ATTD * VV);   // 33.5 MB fp8
    u16*   enc_bf     = (u16*)  alloc((size_t)BB * VV * ENCD * sizeof(u16));   // 33.5 MB
    u16*   escoreT    = (u16*)  alloc((size_t)TT * BB * VV * sizeof(u16));     // 26.2 MB
    float* dpartT     = (float*)alloc((size_t)TT * BB * 2 * sizeof(float));
    float* pawe       = (float*)alloc((size_t)BB * 2 * ENCD * sizeof(float));
    float* dec_att    = (float*)alloc((size_t)BB * ATTD * sizeof(float));
    float* gate0      = (float*)alloc((size_t)BB * ENCD * sizeof(float));
    float* gate1      = (float*)alloc((size_t)BB * ENCD * sizeof(float));
    float* xT         = (float*)alloc((size_t)896 * BB * sizeof(float));
    float* gates_part = (float*)alloc((size_t)6 * BB * 2048 * sizeof(float));  // 3.1 MB
    float* c0         = (float*)alloc((size_t)BB * DECD * sizeof(float));
    float* c1         = (float*)alloc((size_t)BB * DECD * sizeof(float));
    float* W_decT     = (float*)alloc((size_t)DECD * ATTD * sizeof(float));
    float* W_betaT    = (float*)alloc((size_t)DECD * ENCD * sizeof(float));
    float* W2T        = (float*)alloc((size_t)ENCD * 2048 * sizeof(float));
    u32*   bar        = (u32*)  alloc(4096);             // arrival counters + go flags

    hipMemsetAsync(d_out, 0, (size_t)out_size * sizeof(float), stream);
    hipMemsetAsync(bar, 0, 4096, stream);                // reset per launch (graph replay)

    k_transpose<<<1792, 256, 0, stream>>>(W_dec, W_beta, W_ih, W_decT, W_betaT, W2T);
    k_enc_att<<<dim3(VV / 64, BB), 256, 0, stream>>>(enc, W_enc, b_enc, enc_att8, enc_bf);
    k_init<<<BB, 512, 0, stream>>>(enc, lens, captions, emb_W, W_init_h, b_init_h,
                                   W_init_c, b_init_c, W_decT, b_dec, W_betaT, b_beta,
                                   c0, xT, dec_att, gate0, out_len);

    LoopArgs la;
    la.enc_att8 = enc_att8; la.enc_bf = enc_bf; la.w_full = w_full; la.lens = lens;
    la.captions = captions; la.emb_W = emb_W;
    la.W_ih = W_ih; la.W_hh = W_hh; la.b_ih = b_ih; la.b_hh = b_hh;
    la.W2T = W2T; la.W_final = W_final; la.b_final = b_final;
    la.W_decT = W_decT; la.b_dec = b_dec; la.W_betaT = W_betaT; la.b_beta = b_beta;
    la.escoreT = escoreT; la.dpartT = dpartT; la.pawe = pawe; la.gates_part = gates_part;
    la.dec_att = dec_att; la.gate0 = gate0; la.gate1 = gate1; la.c0 = c0; la.c1 = c1;
    la.xT = xT; la.preds = preds; la.bar = bar;
    void* kp[] = { &la };
    hipLaunchCooperativeKernel((const void*)k_loop, dim3(NBLK), dim3(512), kp, 0, stream);

    k_alphas<<<dim3(TT, BB), 256, 0, stream>>>(escoreT, dpartT, lens, alphas);
}